// Round 6
// baseline (854.184 us; speedup 1.0000x reference)
//
#include <hip/hip_runtime.h>
#include <hip/hip_fp16.h>
#include <math.h>

#define H 64
#define FIN 39

__device__ __forceinline__ float bcast(float v, int lane) {
    return __int_as_float(__builtin_amdgcn_readlane(__float_as_int(v), lane));
}

// ---- in-degree, destination-partitioned: group g = blockIdx&7 owns node range g ----
__global__ void k_deg(const int* __restrict__ col, int* __restrict__ deg, int E, int N) {
    int g = blockIdx.x & 7;
    int bg = blockIdx.x >> 3;
    int nbg = gridDim.x >> 3;
    int R = (N + 7) >> 3;
    int lo = g * R;
    int hi = min(N, lo + R);
    for (int e = bg * 256 + threadIdx.x; e < E; e += nbg * 256) {
        int c = col[e];
        if (c >= lo && c < hi) atomicAdd(&deg[c], 1);
    }
}

// ---- scan step 1 ----
__global__ void k_scan1(const int* __restrict__ deg, int* __restrict__ startv,
                        int* __restrict__ bsum, float* __restrict__ cnt, int N) {
    __shared__ int lds[256];
    int tid = threadIdx.x;
    int i = blockIdx.x * 256 + tid;
    int v = (i < N) ? deg[i] : 0;
    if (i < N) cnt[i] = (float)v;
    lds[tid] = v;
    __syncthreads();
    int acc = v;
    for (int off = 1; off < 256; off <<= 1) {
        int t = (tid >= off) ? lds[tid - off] : 0;
        __syncthreads();
        acc += t;
        lds[tid] = acc;
        __syncthreads();
    }
    if (i < N) startv[i] = acc - v;
    if (tid == 255) bsum[blockIdx.x] = acc;
}

// ---- scan step 2 (nb <= 512) ----
__global__ void k_scan2(int* __restrict__ bsum, int nb) {
    __shared__ int lds[512];
    int tid = threadIdx.x;
    int v = (tid < nb) ? bsum[tid] : 0;
    lds[tid] = v;
    __syncthreads();
    int acc = v;
    for (int off = 1; off < 512; off <<= 1) {
        int t = (tid >= off) ? lds[tid - off] : 0;
        __syncthreads();
        acc += t;
        lds[tid] = acc;
        __syncthreads();
    }
    if (tid < nb) bsum[tid] = acc - v;
}

// ---- scan step 3 ----
__global__ void k_scan3(int* __restrict__ startv, const int* __restrict__ bsum,
                        int* __restrict__ cursor, int N) {
    int i = blockIdx.x * 256 + threadIdx.x;
    if (i < N) {
        int s = startv[i] + bsum[blockIdx.x];
        startv[i] = s;
        cursor[i] = s;
    }
}

// ---- fill CSR, destination-partitioned ----
__global__ void k_fill(const int* __restrict__ row, const int* __restrict__ col,
                       int* __restrict__ cursor, int* __restrict__ csr, int E, int N) {
    int g = blockIdx.x & 7;
    int bg = blockIdx.x >> 3;
    int nbg = gridDim.x >> 3;
    int R = (N + 7) >> 3;
    int lo = g * R;
    int hi = min(N, lo + R);
    for (int e = bg * 256 + threadIdx.x; e < E; e += nbg * 256) {
        int c = col[e];
        if (c >= lo && c < hi) {
            int pos = atomicAdd(&cursor[c], 1);
            csr[pos] = row[e];
        }
    }
}

// ---- h = x @ W_in + b_in : 512 thr, 32 nodes/block, 4 nodes/wave, readlane bcast ----
__global__ void k_input(const float* __restrict__ x, const float* __restrict__ Win,
                        const float* __restrict__ bin, float* __restrict__ h, int N) {
    __shared__ float w[FIN * H];
    int tid = threadIdx.x;
    for (int i = tid; i < FIN * H; i += 512) w[i] = Win[i];
    __syncthreads();
    int j = tid & 63;
    int un = __builtin_amdgcn_readfirstlane(blockIdx.x * 32 + (tid >> 6) * 4);
    int n0 = min(un, N - 1), n1 = min(un + 1, N - 1), n2 = min(un + 2, N - 1), n3 = min(un + 3, N - 1);
    float x0 = (j < FIN) ? x[(size_t)n0 * FIN + j] : 0.f;
    float x1 = (j < FIN) ? x[(size_t)n1 * FIN + j] : 0.f;
    float x2 = (j < FIN) ? x[(size_t)n2 * FIN + j] : 0.f;
    float x3 = (j < FIN) ? x[(size_t)n3 * FIN + j] : 0.f;
    float a0 = 0.f, a1 = 0.f, a2 = 0.f, a3 = 0.f;
    #pragma unroll
    for (int k = 0; k < FIN; ++k) {
        float wv = w[k * H + j];
        a0 += bcast(x0, k) * wv;
        a1 += bcast(x1, k) * wv;
        a2 += bcast(x2, k) * wv;
        a3 += bcast(x3, k) * wv;
    }
    float bj = bin[j];
    if (un     < N) h[(size_t)n0 * H + j] = a0 + bj;
    if (un + 1 < N) h[(size_t)n1 * H + j] = a1 + bj;
    if (un + 2 < N) h[(size_t)n2 * H + j] = a2 + bj;
    if (un + 3 < N) h[(size_t)n3 * H + j] = a3 + bj;
}

// ---- A(half) = h @ W_top ; aggr_init = cnt * (h @ W_bot + msg_b) : readlane bcast ----
__global__ void k_AB(const float* __restrict__ h, const float* __restrict__ W,
                     const float* __restrict__ bias, const float* __restrict__ cnt,
                     __half* __restrict__ A, float* __restrict__ aggr, int N) {
    __shared__ float ws[2 * H * H];
    int tid = threadIdx.x;
    {
        const float4* W4 = (const float4*)W;
        float4* s4 = (float4*)ws;
        for (int i = tid; i < 2 * H * H / 4; i += 512) s4[i] = W4[i];
    }
    __syncthreads();
    int j = tid & 63;
    int un = __builtin_amdgcn_readfirstlane(blockIdx.x * 32 + (tid >> 6) * 4);
    int n0 = min(un, N - 1), n1 = min(un + 1, N - 1), n2 = min(un + 2, N - 1), n3 = min(un + 3, N - 1);
    float h0 = h[(size_t)n0 * H + j];
    float h1 = h[(size_t)n1 * H + j];
    float h2 = h[(size_t)n2 * H + j];
    float h3 = h[(size_t)n3 * H + j];
    float a0 = 0.f, a1 = 0.f, a2 = 0.f, a3 = 0.f;
    float b0 = 0.f, b1 = 0.f, b2 = 0.f, b3 = 0.f;
    #pragma unroll
    for (int k = 0; k < H; ++k) {
        float w0 = ws[k * H + j];
        float w1 = ws[(H + k) * H + j];
        float s0 = bcast(h0, k), s1 = bcast(h1, k), s2 = bcast(h2, k), s3 = bcast(h3, k);
        a0 += s0 * w0; b0 += s0 * w1;
        a1 += s1 * w0; b1 += s1 * w1;
        a2 += s2 * w0; b2 += s2 * w1;
        a3 += s3 * w0; b3 += s3 * w1;
    }
    float bj = bias[j];
    if (un < N) {
        A[(size_t)n0 * H + j] = __float2half(a0);
        aggr[(size_t)n0 * H + j] = cnt[n0] * (b0 + bj);
    }
    if (un + 1 < N) {
        A[(size_t)n1 * H + j] = __float2half(a1);
        aggr[(size_t)n1 * H + j] = cnt[n1] * (b1 + bj);
    }
    if (un + 2 < N) {
        A[(size_t)n2 * H + j] = __float2half(a2);
        aggr[(size_t)n2 * H + j] = cnt[n2] * (b2 + bj);
    }
    if (un + 3 < N) {
        A[(size_t)n3 * H + j] = __float2half(a3);
        aggr[(size_t)n3 * H + j] = cnt[n3] * (b3 + bj);
    }
}

// ---- aggr[n][:] += sum over incoming edges of A[src][:]  (CSR gather, fp16 A) ----
__global__ void k_aggr(const int* __restrict__ startv, const int* __restrict__ deg,
                       const int* __restrict__ csr, const __half* __restrict__ A,
                       float* __restrict__ ag, int N) {
    int tid = threadIdx.x;
    int n = __builtin_amdgcn_readfirstlane(blockIdx.x * 4 + (tid >> 6));
    int j = tid & 63;
    if (n >= N) return;
    int s = startv[n];
    int d = deg[n];
    float acc = ag[(size_t)n * H + j];
    int i = 0;
    for (; i + 8 <= d; i += 8) {
        int r0 = csr[s + i + 0], r1 = csr[s + i + 1], r2 = csr[s + i + 2], r3 = csr[s + i + 3];
        int r4 = csr[s + i + 4], r5 = csr[s + i + 5], r6 = csr[s + i + 6], r7 = csr[s + i + 7];
        float v0 = __half2float(A[(size_t)r0 * H + j]);
        float v1 = __half2float(A[(size_t)r1 * H + j]);
        float v2 = __half2float(A[(size_t)r2 * H + j]);
        float v3 = __half2float(A[(size_t)r3 * H + j]);
        float v4 = __half2float(A[(size_t)r4 * H + j]);
        float v5 = __half2float(A[(size_t)r5 * H + j]);
        float v6 = __half2float(A[(size_t)r6 * H + j]);
        float v7 = __half2float(A[(size_t)r7 * H + j]);
        acc += ((v0 + v1) + (v2 + v3)) + ((v4 + v5) + (v6 + v7));
    }
    for (; i < d; ++i) {
        acc += __half2float(A[(size_t)csr[s + i] * H + j]);
    }
    ag[(size_t)n * H + j] = acc;
}

// ---- upd + LN (+ fused out MLP) : 512 thr, readlane bcast ----
template<bool DO_OUT>
__global__ void k_upd(const float* __restrict__ hin, const float* __restrict__ ag,
                      const float* __restrict__ cnt, const float* __restrict__ W,
                      const float* __restrict__ bias, const float* __restrict__ g,
                      const float* __restrict__ beta, float* __restrict__ hout,
                      const float* __restrict__ W1, const float* __restrict__ b1,
                      const float* __restrict__ W2, const float* __restrict__ b2,
                      float* __restrict__ out, int N) {
    __shared__ float ws[2 * H * H];
    __shared__ float w1s[DO_OUT ? H * 32 : 1];
    __shared__ float w2s[DO_OUT ? 32 : 1];
    __shared__ float b1s[DO_OUT ? 32 : 1];
    __shared__ float hs[DO_OUT ? 32 * H : 1];
    int tid = threadIdx.x;
    {
        const float4* W4 = (const float4*)W;
        float4* s4 = (float4*)ws;
        for (int i = tid; i < 2 * H * H / 4; i += 512) s4[i] = W4[i];
    }
    if (DO_OUT) {
        for (int i = tid; i < H * 32; i += 512) w1s[i] = W1[i];
        if (tid < 32) { w2s[tid] = W2[tid]; b1s[tid] = b1[tid]; }
    }
    __syncthreads();
    int j = tid & 63;
    int ln = tid >> 6;
    int un = __builtin_amdgcn_readfirstlane(blockIdx.x * 32 + ln * 4);
    int n0 = min(un, N - 1), n1 = min(un + 1, N - 1), n2 = min(un + 2, N - 1), n3 = min(un + 3, N - 1);
    float h0 = hin[(size_t)n0 * H + j];
    float h1 = hin[(size_t)n1 * H + j];
    float h2 = hin[(size_t)n2 * H + j];
    float h3 = hin[(size_t)n3 * H + j];
    float g0 = ag[(size_t)n0 * H + j];
    float g1 = ag[(size_t)n1 * H + j];
    float g2 = ag[(size_t)n2 * H + j];
    float g3 = ag[(size_t)n3 * H + j];
    float uH0 = 0.f, uH1 = 0.f, uH2 = 0.f, uH3 = 0.f;
    float uA0 = 0.f, uA1 = 0.f, uA2 = 0.f, uA3 = 0.f;
    #pragma unroll
    for (int k = 0; k < H; ++k) {
        float w0 = ws[k * H + j];
        float w1 = ws[(H + k) * H + j];
        uH0 += bcast(h0, k) * w0; uA0 += bcast(g0, k) * w1;
        uH1 += bcast(h1, k) * w0; uA1 += bcast(g1, k) * w1;
        uH2 += bcast(h2, k) * w0; uA2 += bcast(g2, k) * w1;
        uH3 += bcast(h3, k) * w0; uA3 += bcast(g3, k) * w1;
    }
    float bj = bias[j], gj = g[j], betaj = beta[j];
    #pragma unroll
    for (int q = 0; q < 4; ++q) {
        int n = un + q;
        if (n < N) {
            float accH = (q == 0) ? uH0 : (q == 1) ? uH1 : (q == 2) ? uH2 : uH3;
            float accA = (q == 0) ? uA0 : (q == 1) ? uA1 : (q == 2) ? uA2 : uA3;
            float hv   = (q == 0) ? h0  : (q == 1) ? h1  : (q == 2) ? h2  : h3;
            float rd = 1.0f / fmaxf(cnt[n], 1.0f);
            float z = hv + accH + rd * accA + bj;
            float s = z;
            for (int o = 32; o > 0; o >>= 1) s += __shfl_xor(s, o);
            float mu = s * (1.0f / H);
            float d = z - mu;
            float v = d * d;
            for (int o = 32; o > 0; o >>= 1) v += __shfl_xor(v, o);
            float var = v * (1.0f / H);
            float r = rsqrtf(var + 1e-5f);
            float hval = d * r * gj + betaj;
            if (DO_OUT) hs[(ln * 4 + q) * H + j] = hval;
            else        hout[(size_t)n * H + j] = hval;
        }
    }
    if (DO_OUT) {
        __syncthreads();
        int hf = j >> 5, jj = j & 31;
        #pragma unroll
        for (int q = 0; q < 4; ++q) {
            int n = un + q;
            if (n >= N) continue;
            int nbl = ln * 4 + q;
            float t = 0.f;
            #pragma unroll
            for (int kk = 0; kk < 32; ++kk) {
                int k = hf * 32 + kk;
                t += hs[nbl * H + k] * w1s[k * 32 + jj];
            }
            t += __shfl_xor(t, 32);
            float t2 = t + b1s[jj];
            float ge = 0.5f * t2 * (1.0f + erff(t2 * 0.70710678118654752f)) * w2s[jj];
            for (int o = 16; o > 0; o >>= 1) ge += __shfl_xor(ge, o);
            if (j == 0) out[n] = 1.0f / (1.0f + expf(-(ge + b2[0])));
        }
    }
}

extern "C" void kernel_launch(void* const* d_in, const int* in_sizes, int n_in,
                              void* d_out, int out_size, void* d_ws, size_t ws_size,
                              hipStream_t stream) {
    const float* x    = (const float*)d_in[0];
    const int*   ei   = (const int*)d_in[1];
    const float* Win  = (const float*)d_in[2];
    const float* bin  = (const float*)d_in[3];
    const float* msgW = (const float*)d_in[4];
    const float* msgb = (const float*)d_in[5];
    const float* updW = (const float*)d_in[6];
    const float* updb = (const float*)d_in[7];
    const float* lng  = (const float*)d_in[8];
    const float* lnb  = (const float*)d_in[9];
    const float* W1   = (const float*)d_in[10];
    const float* b1   = (const float*)d_in[11];
    const float* W2   = (const float*)d_in[12];
    const float* b2   = (const float*)d_in[13];

    int N = in_sizes[0] / FIN;
    int E = in_sizes[1] / 2;
    const int* row = ei;
    const int* col = ei + E;

    float* wsp  = (float*)d_ws;
    float* cnt  = wsp;                        // N
    float* X    = wsp + N;                    // N*H
    float* Y    = X + (size_t)N * H;          // N*H
    float* Z    = Y + (size_t)N * H;          // N*H  (aggr)
    __half* Ah  = (__half*)(Z + (size_t)N * H);            // N*H halves
    int* deg    = (int*)(Ah + (size_t)N * H); // N
    int* startv = deg + N;                    // N
    int* cursor = startv + N;                 // N
    int* bsum   = cursor + N;                 // 512
    int* csr    = bsum + 512;                 // E

    int nb = (N + 255) / 256;
    int nb32 = (N + 31) / 32;

    hipMemsetAsync(deg, 0, (size_t)N * sizeof(int), stream);
    k_deg<<<1024, 256, 0, stream>>>(col, deg, E, N);
    k_scan1<<<nb, 256, 0, stream>>>(deg, startv, bsum, cnt, N);
    k_scan2<<<1, 512, 0, stream>>>(bsum, nb);
    k_scan3<<<nb, 256, 0, stream>>>(startv, bsum, cursor, N);
    k_fill<<<1024, 256, 0, stream>>>(row, col, cursor, csr, E, N);

    k_input<<<nb32, 512, 0, stream>>>(x, Win, bin, X, N);

    // layer 0: h=X, A->Ah, aggr->Z, hout->Y
    k_AB<<<nb32, 512, 0, stream>>>(X, msgW, msgb, cnt, Ah, Z, N);
    k_aggr<<<(N + 3) / 4, 256, 0, stream>>>(startv, deg, csr, Ah, Z, N);
    k_upd<false><<<nb32, 512, 0, stream>>>(X, Z, cnt, updW, updb, lng, lnb, Y,
                                           nullptr, nullptr, nullptr, nullptr, nullptr, N);

    // layer 1: h=Y, A->Ah, aggr->Z, fused final MLP -> d_out
    k_AB<<<nb32, 512, 0, stream>>>(Y, msgW + 2 * H * H, msgb + H, cnt, Ah, Z, N);
    k_aggr<<<(N + 3) / 4, 256, 0, stream>>>(startv, deg, csr, Ah, Z, N);
    k_upd<true><<<nb32, 512, 0, stream>>>(Y, Z, cnt, updW + 2 * H * H, updb + H,
                                          lng + H, lnb + H, X,
                                          W1, b1, W2, b2, (float*)d_out, N);
}

// Round 7
// 350.014 us; speedup vs baseline: 2.4404x; 2.4404x over previous
//
#include <hip/hip_runtime.h>
#include <math.h>

#define H 64
#define FIN 39

typedef _Float16 half8 __attribute__((ext_vector_type(8)));
typedef float floatx4 __attribute__((ext_vector_type(4)));

// ---- in-degree, destination-partitioned ----
__global__ void k_deg(const int* __restrict__ col, int* __restrict__ deg, int E, int N) {
    int g = blockIdx.x & 7;
    int bg = blockIdx.x >> 3;
    int nbg = gridDim.x >> 3;
    int R = (N + 7) >> 3;
    int lo = g * R;
    int hi = min(N, lo + R);
    for (int e = bg * 256 + threadIdx.x; e < E; e += nbg * 256) {
        int c = col[e];
        if (c >= lo && c < hi) atomicAdd(&deg[c], 1);
    }
}

// ---- scan step 1 ----
__global__ void k_scan1(const int* __restrict__ deg, int* __restrict__ startv,
                        int* __restrict__ bsum, float* __restrict__ cnt, int N) {
    __shared__ int lds[256];
    int tid = threadIdx.x;
    int i = blockIdx.x * 256 + tid;
    int v = (i < N) ? deg[i] : 0;
    if (i < N) cnt[i] = (float)v;
    lds[tid] = v;
    __syncthreads();
    int acc = v;
    for (int off = 1; off < 256; off <<= 1) {
        int t = (tid >= off) ? lds[tid - off] : 0;
        __syncthreads();
        acc += t;
        lds[tid] = acc;
        __syncthreads();
    }
    if (i < N) startv[i] = acc - v;
    if (tid == 255) bsum[blockIdx.x] = acc;
}

// ---- scan step 2 (nb <= 512) ----
__global__ void k_scan2(int* __restrict__ bsum, int nb) {
    __shared__ int lds[512];
    int tid = threadIdx.x;
    int v = (tid < nb) ? bsum[tid] : 0;
    lds[tid] = v;
    __syncthreads();
    int acc = v;
    for (int off = 1; off < 512; off <<= 1) {
        int t = (tid >= off) ? lds[tid - off] : 0;
        __syncthreads();
        acc += t;
        lds[tid] = acc;
        __syncthreads();
    }
    if (tid < nb) bsum[tid] = acc - v;
}

// ---- scan step 3 ----
__global__ void k_scan3(int* __restrict__ startv, const int* __restrict__ bsum,
                        int* __restrict__ cursor, int N) {
    int i = blockIdx.x * 256 + threadIdx.x;
    if (i < N) {
        int s = startv[i] + bsum[blockIdx.x];
        startv[i] = s;
        cursor[i] = s;
    }
}

// ---- fill CSR, destination-partitioned ----
__global__ void k_fill(const int* __restrict__ row, const int* __restrict__ col,
                       int* __restrict__ cursor, int* __restrict__ csr, int E, int N) {
    int g = blockIdx.x & 7;
    int bg = blockIdx.x >> 3;
    int nbg = gridDim.x >> 3;
    int R = (N + 7) >> 3;
    int lo = g * R;
    int hi = min(N, lo + R);
    for (int e = bg * 256 + threadIdx.x; e < E; e += nbg * 256) {
        int c = col[e];
        if (c >= lo && c < hi) {
            int pos = atomicAdd(&cursor[c], 1);
            csr[pos] = row[e];
        }
    }
}

// ---- pack W [128][64] fp32 -> MFMA B-fragments fp16 ----
// frag fidx = half*8 + s*4 + t ; entry (fidx, lane l): k = 64*half + 32*s + (l>>4)*8 + i,
// col = 16*t + (l&15)
__global__ void k_packW(const float* __restrict__ msgW, const float* __restrict__ updW,
                        _Float16* __restrict__ wpk) {
    int mat = blockIdx.x;  // 0: msg l0, 1: msg l1, 2: upd l0, 3: upd l1
    const float* W = (mat < 2) ? (msgW + (size_t)mat * 2 * H * H)
                               : (updW + (size_t)(mat - 2) * 2 * H * H);
    _Float16* dst = wpk + (size_t)mat * 16 * 64 * 8;
    for (int e = threadIdx.x; e < 16 * 64; e += 256) {
        int fidx = e >> 6;
        int l = e & 63;
        int hf = fidx >> 3;
        int s = (fidx >> 2) & 1;
        int t = fidx & 3;
        int kbase = hf * 64 + s * 32 + ((l >> 4) * 8);
        int c = t * 16 + (l & 15);
        _Float16* d = dst + (size_t)e * 8;
        #pragma unroll
        for (int i = 0; i < 8; ++i)
            d[i] = (_Float16)W[(size_t)(kbase + i) * H + c];
    }
}

// ---- h16 = fp16(x @ W_in + b_in) : 512 thr, 32 nodes/block ----
__global__ void k_input(const float* __restrict__ x, const float* __restrict__ Win,
                        const float* __restrict__ bin, _Float16* __restrict__ h16, int N) {
    __shared__ float w[FIN * H];
    int tid = threadIdx.x;
    for (int i = tid; i < FIN * H; i += 512) w[i] = Win[i];
    __syncthreads();
    int j = tid & 63;
    int un = __builtin_amdgcn_readfirstlane(blockIdx.x * 32 + (tid >> 6) * 4);
    int n0 = min(un, N - 1), n1 = min(un + 1, N - 1), n2 = min(un + 2, N - 1), n3 = min(un + 3, N - 1);
    const float* x0 = x + (size_t)n0 * FIN;
    const float* x1 = x + (size_t)n1 * FIN;
    const float* x2 = x + (size_t)n2 * FIN;
    const float* x3 = x + (size_t)n3 * FIN;
    float a0 = 0.f, a1 = 0.f, a2 = 0.f, a3 = 0.f;
    #pragma unroll
    for (int k = 0; k < FIN; ++k) {
        float wv = w[k * H + j];
        a0 += x0[k] * wv;
        a1 += x1[k] * wv;
        a2 += x2[k] * wv;
        a3 += x3[k] * wv;
    }
    float bj = bin[j];
    if (un     < N) h16[(size_t)n0 * H + j] = (_Float16)(a0 + bj);
    if (un + 1 < N) h16[(size_t)n1 * H + j] = (_Float16)(a1 + bj);
    if (un + 2 < N) h16[(size_t)n2 * H + j] = (_Float16)(a2 + bj);
    if (un + 3 < N) h16[(size_t)n3 * H + j] = (_Float16)(a3 + bj);
}

// ---- MFMA: A(fp16) = h@W_top ; aggr_init = cnt*(h@W_bot + msg_b) ----
// 256 thr = 4 waves, 16 nodes/wave, 64 nodes/block. No LDS.
__global__ __launch_bounds__(256) void k_AB(const _Float16* __restrict__ h16,
        const _Float16* __restrict__ wpk, const float* __restrict__ bias,
        const float* __restrict__ cnt, _Float16* __restrict__ A,
        float* __restrict__ ag, int N) {
    int l = threadIdx.x & 63;
    int w = threadIdx.x >> 6;
    int n0 = blockIdx.x * 64 + w * 16;
    int mrow = l & 15, kgrp = l >> 4;
    int nA = min(n0 + mrow, N - 1);
    half8 ah0 = *(const half8*)(h16 + (size_t)nA * H + kgrp * 8);
    half8 ah1 = *(const half8*)(h16 + (size_t)nA * H + 32 + kgrp * 8);
    floatx4 accA[4] = {};
    floatx4 accB[4] = {};
    #pragma unroll
    for (int s = 0; s < 2; ++s) {
        half8 a = s ? ah1 : ah0;
        #pragma unroll
        for (int t = 0; t < 4; ++t) {
            half8 bt = *(const half8*)(wpk + ((size_t)((s * 4 + t) * 64 + l)) * 8);
            half8 bb = *(const half8*)(wpk + ((size_t)((8 + s * 4 + t) * 64 + l)) * 8);
            accA[t] = __builtin_amdgcn_mfma_f32_16x16x32_f16(a, bt, accA[t], 0, 0, 0);
            accB[t] = __builtin_amdgcn_mfma_f32_16x16x32_f16(a, bb, accB[t], 0, 0, 0);
        }
    }
    float bl[4];
    #pragma unroll
    for (int t = 0; t < 4; ++t) bl[t] = bias[t * 16 + mrow];
    #pragma unroll
    for (int r = 0; r < 4; ++r) {
        int n = n0 + kgrp * 4 + r;
        if (n < N) {
            float c = cnt[n];
            #pragma unroll
            for (int t = 0; t < 4; ++t) {
                int j = t * 16 + mrow;
                A[(size_t)n * H + j] = (_Float16)accA[t][r];
                ag[(size_t)n * H + j] = c * (accB[t][r] + bl[t]);
            }
        }
    }
}

// ---- aggr[n][:] += sum over incoming edges of A[src][:] (CSR gather, fp16 A) ----
__global__ void k_aggr(const int* __restrict__ startv, const int* __restrict__ deg,
                       const int* __restrict__ csr, const _Float16* __restrict__ A,
                       float* __restrict__ ag, int N) {
    int tid = threadIdx.x;
    int n = __builtin_amdgcn_readfirstlane(blockIdx.x * 4 + (tid >> 6));
    int j = tid & 63;
    if (n >= N) return;
    int s = startv[n];
    int d = deg[n];
    float acc = ag[(size_t)n * H + j];
    int i = 0;
    for (; i + 8 <= d; i += 8) {
        int r0 = csr[s + i + 0], r1 = csr[s + i + 1], r2 = csr[s + i + 2], r3 = csr[s + i + 3];
        int r4 = csr[s + i + 4], r5 = csr[s + i + 5], r6 = csr[s + i + 6], r7 = csr[s + i + 7];
        float v0 = (float)A[(size_t)r0 * H + j];
        float v1 = (float)A[(size_t)r1 * H + j];
        float v2 = (float)A[(size_t)r2 * H + j];
        float v3 = (float)A[(size_t)r3 * H + j];
        float v4 = (float)A[(size_t)r4 * H + j];
        float v5 = (float)A[(size_t)r5 * H + j];
        float v6 = (float)A[(size_t)r6 * H + j];
        float v7 = (float)A[(size_t)r7 * H + j];
        acc += ((v0 + v1) + (v2 + v3)) + ((v4 + v5) + (v6 + v7));
    }
    for (; i < d; ++i) {
        acc += (float)A[(size_t)csr[s + i] * H + j];
    }
    ag[(size_t)n * H + j] = acc;
}

// ---- MFMA upd + LN (+ fused out MLP) : 256 thr, 64 nodes/block ----
template<bool DO_OUT>
__global__ __launch_bounds__(256) void k_upd(const _Float16* __restrict__ h16in,
        const float* __restrict__ ag, const float* __restrict__ cnt,
        const _Float16* __restrict__ wpk, const float* __restrict__ bias,
        const float* __restrict__ lng, const float* __restrict__ lnb,
        _Float16* __restrict__ h16out,
        const float* __restrict__ W1, const float* __restrict__ b1,
        const float* __restrict__ W2, const float* __restrict__ b2,
        float* __restrict__ out, int N) {
    __shared__ float w1s[DO_OUT ? H * 32 : 1];
    __shared__ float hsmem[DO_OUT ? 4 * 16 * H : 1];
    if (DO_OUT) {
        for (int i = threadIdx.x; i < H * 32; i += 256) w1s[i] = W1[i];
    }
    int l = threadIdx.x & 63;
    int w = threadIdx.x >> 6;
    int n0 = blockIdx.x * 64 + w * 16;
    int mrow = l & 15, kgrp = l >> 4;
    int nA = min(n0 + mrow, N - 1);
    half8 ah0 = *(const half8*)(h16in + (size_t)nA * H + kgrp * 8);
    half8 ah1 = *(const half8*)(h16in + (size_t)nA * H + 32 + kgrp * 8);
    float rd = 1.0f / fmaxf(cnt[nA], 1.0f);
    half8 agf[2];
    #pragma unroll
    for (int s = 0; s < 2; ++s) {
        const float* gp = ag + (size_t)nA * H + s * 32 + kgrp * 8;
        float4 g0 = *(const float4*)gp;
        float4 g1 = *(const float4*)(gp + 4);
        half8 v;
        v[0] = (_Float16)(g0.x * rd); v[1] = (_Float16)(g0.y * rd);
        v[2] = (_Float16)(g0.z * rd); v[3] = (_Float16)(g0.w * rd);
        v[4] = (_Float16)(g1.x * rd); v[5] = (_Float16)(g1.y * rd);
        v[6] = (_Float16)(g1.z * rd); v[7] = (_Float16)(g1.w * rd);
        agf[s] = v;
    }
    floatx4 acc[4] = {};
    #pragma unroll
    for (int s = 0; s < 2; ++s) {
        half8 a = s ? ah1 : ah0;
        half8 gfr = agf[s];
        #pragma unroll
        for (int t = 0; t < 4; ++t) {
            half8 bt = *(const half8*)(wpk + ((size_t)((s * 4 + t) * 64 + l)) * 8);
            half8 bb = *(const half8*)(wpk + ((size_t)((8 + s * 4 + t) * 64 + l)) * 8);
            acc[t] = __builtin_amdgcn_mfma_f32_16x16x32_f16(a, bt, acc[t], 0, 0, 0);
            acc[t] = __builtin_amdgcn_mfma_f32_16x16x32_f16(gfr, bb, acc[t], 0, 0, 0);
        }
    }
    float bl[4], gl[4], bb2[4];
    #pragma unroll
    for (int t = 0; t < 4; ++t) {
        int j = t * 16 + mrow;
        bl[t] = bias[j]; gl[t] = lng[j]; bb2[t] = lnb[j];
    }
    float zt[4][4];  // [t][r]
    #pragma unroll
    for (int r = 0; r < 4; ++r) {
        int n = min(n0 + kgrp * 4 + r, N - 1);
        #pragma unroll
        for (int t = 0; t < 4; ++t) {
            float hv = (float)h16in[(size_t)n * H + t * 16 + mrow];
            zt[t][r] = hv + acc[t][r] + bl[t];
        }
    }
    #pragma unroll
    for (int r = 0; r < 4; ++r) {
        float s = zt[0][r] + zt[1][r] + zt[2][r] + zt[3][r];
        s += __shfl_xor(s, 1); s += __shfl_xor(s, 2);
        s += __shfl_xor(s, 4); s += __shfl_xor(s, 8);
        float mu = s * (1.0f / H);
        float v = 0.f;
        #pragma unroll
        for (int t = 0; t < 4; ++t) { float d = zt[t][r] - mu; v += d * d; }
        v += __shfl_xor(v, 1); v += __shfl_xor(v, 2);
        v += __shfl_xor(v, 4); v += __shfl_xor(v, 8);
        float rinv = rsqrtf(v * (1.0f / H) + 1e-5f);
        int m = kgrp * 4 + r;
        int n = n0 + m;
        #pragma unroll
        for (int t = 0; t < 4; ++t) {
            float hval = (zt[t][r] - mu) * rinv * gl[t] + bb2[t];
            if (DO_OUT) hsmem[(w * 16 + m) * H + t * 16 + mrow] = hval;
            else if (n < N) h16out[(size_t)n * H + t * 16 + mrow] = (_Float16)hval;
        }
    }
    if (DO_OUT) {
        __syncthreads();
        int hf = l >> 5, jj = l & 31;
        float w2v = W2[jj];
        float b1v = b1[jj];
        float b2v = b2[0];
        for (int nn = 0; nn < 16; ++nn) {
            int n = n0 + nn;
            if (n >= N) continue;
            const float* hrow = &hsmem[(w * 16 + nn) * H];
            float t = 0.f;
            #pragma unroll
            for (int kk = 0; kk < 32; ++kk)
                t += hrow[hf * 32 + kk] * w1s[(hf * 32 + kk) * 32 + jj];
            t += __shfl_xor(t, 32);
            float t2 = t + b1v;
            float ge = 0.5f * t2 * (1.0f + erff(t2 * 0.70710678118654752f)) * w2v;
            ge += __shfl_xor(ge, 16); ge += __shfl_xor(ge, 8);
            ge += __shfl_xor(ge, 4);  ge += __shfl_xor(ge, 2);
            ge += __shfl_xor(ge, 1);
            if (l == 0) out[n] = 1.0f / (1.0f + expf(-(ge + b2v)));
        }
    }
}

extern "C" void kernel_launch(void* const* d_in, const int* in_sizes, int n_in,
                              void* d_out, int out_size, void* d_ws, size_t ws_size,
                              hipStream_t stream) {
    const float* x    = (const float*)d_in[0];
    const int*   ei   = (const int*)d_in[1];
    const float* Win  = (const float*)d_in[2];
    const float* bin  = (const float*)d_in[3];
    const float* msgW = (const float*)d_in[4];
    const float* msgb = (const float*)d_in[5];
    const float* updW = (const float*)d_in[6];
    const float* updb = (const float*)d_in[7];
    const float* lng  = (const float*)d_in[8];
    const float* lnb  = (const float*)d_in[9];
    const float* W1   = (const float*)d_in[10];
    const float* b1   = (const float*)d_in[11];
    const float* W2   = (const float*)d_in[12];
    const float* b2   = (const float*)d_in[13];

    int N = in_sizes[0] / FIN;
    int E = in_sizes[1] / 2;
    const int* row = ei;
    const int* col = ei + E;

    float* wsp  = (float*)d_ws;
    float* cnt  = wsp;                          // N f32
    float* Z    = wsp + N;                      // N*H f32 (aggr)
    _Float16* Ah   = (_Float16*)(Z + (size_t)N * H);   // N*H f16 (messages)
    _Float16* h16a = Ah + (size_t)N * H;        // N*H f16
    _Float16* h16b = h16a + (size_t)N * H;      // N*H f16
    _Float16* wpk  = h16b + (size_t)N * H;      // 4*16*64*8 f16 = 64KB
    int* deg    = (int*)(wpk + 4 * 16 * 64 * 8);// N
    int* startv = deg + N;                      // N
    int* cursor = startv + N;                   // N
    int* bsum   = cursor + N;                   // 512
    int* csr    = bsum + 512;                   // E

    int nb = (N + 255) / 256;
    int nb64 = (N + 63) / 64;

    hipMemsetAsync(deg, 0, (size_t)N * sizeof(int), stream);
    k_packW<<<4, 256, 0, stream>>>(msgW, updW, wpk);
    k_deg<<<1024, 256, 0, stream>>>(col, deg, E, N);
    k_scan1<<<nb, 256, 0, stream>>>(deg, startv, bsum, cnt, N);
    k_scan2<<<1, 512, 0, stream>>>(bsum, nb);
    k_scan3<<<nb, 256, 0, stream>>>(startv, bsum, cursor, N);
    k_fill<<<1024, 256, 0, stream>>>(row, col, cursor, csr, E, N);

    k_input<<<(N + 31) / 32, 512, 0, stream>>>(x, Win, bin, h16a, N);

    // layer 0: h=h16a -> A->Ah, aggr->Z, hout->h16b
    k_AB<<<nb64, 256, 0, stream>>>(h16a, wpk + 0 * 8192, msgb, cnt, Ah, Z, N);
    k_aggr<<<(N + 3) / 4, 256, 0, stream>>>(startv, deg, csr, Ah, Z, N);
    k_upd<false><<<nb64, 256, 0, stream>>>(h16a, Z, cnt, wpk + 2 * 8192, updb, lng, lnb,
                                           h16b, nullptr, nullptr, nullptr, nullptr,
                                           nullptr, N);

    // layer 1: h=h16b -> A->Ah, aggr->Z, fused final MLP -> d_out
    k_AB<<<nb64, 256, 0, stream>>>(h16b, wpk + 1 * 8192, msgb + H, cnt, Ah, Z, N);
    k_aggr<<<(N + 3) / 4, 256, 0, stream>>>(startv, deg, csr, Ah, Z, N);
    k_upd<true><<<nb64, 256, 0, stream>>>(h16b, Z, cnt, wpk + 3 * 8192, updb + H,
                                          lng + H, lnb + H, nullptr,
                                          W1, b1, W2, b2, (float*)d_out, N);
}